// Round 5
// baseline (482.793 us; speedup 1.0000x reference)
//
#include <hip/hip_runtime.h>
#include <hip/hip_bf16.h>

#define D_IN_C 16
#define BUCKET_SHIFT 9
#define BUCKET_NODES 512           // 1 << BUCKET_SHIFT
#define CAP 18432                  // per-bucket capacity (mean 16384 + 16 sigma), mult of 8
#define PT 16                      // edges per thread in partition kernel
#define PART_CHUNK 4096            // 256 * PT

typedef int v4i __attribute__((ext_vector_type(4)));

// ---------------- Kernel 1: MLP + zero bcur ----------------
__global__ __launch_bounds__(256) void mlp_kernel(
    const float* __restrict__ x,
    const float* __restrict__ w1, const float* __restrict__ b1,
    const float* __restrict__ w2, const float* __restrict__ b2,
    float* __restrict__ h, int* __restrict__ bcur,
    int n_nodes) {
  __shared__ float sw1[256];
  __shared__ float sw2[256];
  __shared__ float sb1[16];
  __shared__ float sb2[16];
  int t = threadIdx.x;
  if (blockIdx.x == 0) bcur[t] = 0;   // 256 >= nbuck
  sw1[t] = w1[t];
  sw2[t] = w2[t];
  if (t < 16) { sb1[t] = b1[t]; sb2[t] = b2[t]; }
  __syncthreads();

  int n = blockIdx.x * blockDim.x + t;
  if (n >= n_nodes) return;

  float xi[16];
  const float4* xr = (const float4*)(x + (size_t)n * 16);
  float4 v0 = xr[0], v1 = xr[1], v2 = xr[2], v3 = xr[3];
  xi[0]=v0.x; xi[1]=v0.y; xi[2]=v0.z; xi[3]=v0.w;
  xi[4]=v1.x; xi[5]=v1.y; xi[6]=v1.z; xi[7]=v1.w;
  xi[8]=v2.x; xi[9]=v2.y; xi[10]=v2.z; xi[11]=v2.w;
  xi[12]=v3.x; xi[13]=v3.y; xi[14]=v3.z; xi[15]=v3.w;

  float t1[16];
#pragma unroll
  for (int j = 0; j < 16; ++j) {
    float acc = sb1[j];
#pragma unroll
    for (int k = 0; k < 16; ++k) acc += xi[k] * sw1[k * 16 + j];
    t1[j] = fmaxf(acc, 0.0f);
  }
  float hh[16];
#pragma unroll
  for (int j = 0; j < 16; ++j) {
    float acc = sb2[j];
#pragma unroll
    for (int k = 0; k < 16; ++k) acc += t1[k] * sw2[k * 16 + j];
    hh[j] = acc;
  }

  float4* hw = (float4*)(h + (size_t)n * 16);
  hw[0] = make_float4(hh[0], hh[1], hh[2], hh[3]);
  hw[1] = make_float4(hh[4], hh[5], hh[6], hh[7]);
  hw[2] = make_float4(hh[8], hh[9], hh[10], hh[11]);
  hw[3] = make_float4(hh[12], hh[13], hh[14], hh[15]);
}

// ---------------- Kernel 2: bucket partition (LDS hist + range reserve) ----------------
__global__ __launch_bounds__(256) void part_kernel(
    const int* __restrict__ src, const int* __restrict__ dst,
    int* __restrict__ bcur, int* __restrict__ part,
    int* __restrict__ cnt, int nbuck, int n_edges) {
  __shared__ int lhist[256];
  __shared__ int lofs[256];
  int t = threadIdx.x;
  int base = blockIdx.x * PART_CHUNK;

  // zero the global degree array (consumed by acc_kernel later in the stream)
  int zi = blockIdx.x * 256 + t;
  if (zi < nbuck * BUCKET_NODES) cnt[zi] = 0;

  if (t < nbuck) lhist[t] = 0;
  __syncthreads();

  int d[PT], s[PT];
#pragma unroll
  for (int i = 0; i < PT; ++i) {
    int e = base + i * 256 + t;
    if (e < n_edges) { d[i] = dst[e]; s[i] = src[e]; }
    else d[i] = -1;
  }
#pragma unroll
  for (int i = 0; i < PT; ++i) {
    if (d[i] >= 0) atomicAdd(&lhist[d[i] >> BUCKET_SHIFT], 1);
  }
  __syncthreads();
  if (t < nbuck) {
    int c = lhist[t];
    int r = (c > 0) ? atomicAdd(&bcur[t], c) : 0;
    lofs[t] = t * CAP + r;
  }
  __syncthreads();
#pragma unroll
  for (int i = 0; i < PT; ++i) {
    if (d[i] >= 0) {
      int b = d[i] >> BUCKET_SHIFT;
      int p = atomicAdd(&lofs[b], 1);
      part[p] = ((d[i] & (BUCKET_NODES - 1)) << 17) | s[i];
    }
  }
}

// ---------------- Kernel 3: per-bucket LDS accumulation ----------------
// grid = nbuck * C, 256 threads (4 waves). LDS: 512x16 f32 (32KB) + 512 deg (2KB).
// The gathers are issued from INLINE ASM (8 loads then one s_waitcnt) so the
// compiler cannot re-serialize them (R3: guarded loads -> MLP=1, 347us;
// R4: branch-free but scheduler minimized VGPRs to 16 -> MLP=1, 308us).
__global__ __launch_bounds__(256, 4) void acc_kernel(
    const float* __restrict__ h, const int* __restrict__ part,
    const int* __restrict__ bcur, int* __restrict__ cnt,
    float* __restrict__ partial,   // C buffers, each nbuck*512*16 floats
    int nbuck, int C) {
  __shared__ float acc[BUCKET_NODES * 16];
  __shared__ int dcnt[BUCKET_NODES];
  int t = threadIdx.x;
  int b = blockIdx.x / C;
  int c = blockIdx.x % C;

  float4* accz = (float4*)acc;
#pragma unroll
  for (int i = t; i < BUCKET_NODES * 4; i += 256)
    accz[i] = make_float4(0.f, 0.f, 0.f, 0.f);
  dcnt[t] = 0;
  dcnt[t + 256] = 0;
  __syncthreads();

  int count = bcur[b];
  // chunk boundaries rounded down to multiples of 8 so int4 index loads stay aligned
  int s0 = (int)((long long)count * c / C) & ~7;
  int s1 = (c + 1 == C) ? count : ((int)((long long)count * (c + 1) / C) & ~7);
  int start = b * CAP + s0;
  int end   = b * CAP + s1;

  int g = t >> 4;      // 0..15 edge-group
  int k = t & 15;      // feature

  int nfull = (end - start) >> 7;   // full 128-edge chunks (16 groups x 8 edges)
  int e = start;
  for (int f = 0; f < nfull; ++f, e += 128) {
    const int* pp = part + e + g * 8;
    v4i pa, pb;
    asm volatile(
        "global_load_dwordx4 %0, %[q0], off\n\t"
        "global_load_dwordx4 %1, %[q1], off\n\t"
        "s_waitcnt vmcnt(0)"
        : "=&v"(pa), "=&v"(pb)
        : [q0] "v"(pp), [q1] "v"(pp + 4)
        : "memory");

    const float* p0 = h + ((((unsigned)pa.x & 0x1FFFFu) << 4) | (unsigned)k);
    const float* p1 = h + ((((unsigned)pa.y & 0x1FFFFu) << 4) | (unsigned)k);
    const float* p2 = h + ((((unsigned)pa.z & 0x1FFFFu) << 4) | (unsigned)k);
    const float* p3 = h + ((((unsigned)pa.w & 0x1FFFFu) << 4) | (unsigned)k);
    const float* p4 = h + ((((unsigned)pb.x & 0x1FFFFu) << 4) | (unsigned)k);
    const float* p5 = h + ((((unsigned)pb.y & 0x1FFFFu) << 4) | (unsigned)k);
    const float* p6 = h + ((((unsigned)pb.z & 0x1FFFFu) << 4) | (unsigned)k);
    const float* p7 = h + ((((unsigned)pb.w & 0x1FFFFu) << 4) | (unsigned)k);

    float v0, v1, v2, v3, v4, v5, v6, v7;
    asm volatile(
        "global_load_dword %0, %[a0], off\n\t"
        "global_load_dword %1, %[a1], off\n\t"
        "global_load_dword %2, %[a2], off\n\t"
        "global_load_dword %3, %[a3], off\n\t"
        "global_load_dword %4, %[a4], off\n\t"
        "global_load_dword %5, %[a5], off\n\t"
        "global_load_dword %6, %[a6], off\n\t"
        "global_load_dword %7, %[a7], off\n\t"
        "s_waitcnt vmcnt(0)"
        : "=&v"(v0), "=&v"(v1), "=&v"(v2), "=&v"(v3),
          "=&v"(v4), "=&v"(v5), "=&v"(v6), "=&v"(v7)
        : [a0] "v"(p0), [a1] "v"(p1), [a2] "v"(p2), [a3] "v"(p3),
          [a4] "v"(p4), [a5] "v"(p5), [a6] "v"(p6), [a7] "v"(p7)
        : "memory");

    atomicAdd(&acc[((((unsigned)pa.x) >> 17) << 4) | (unsigned)k], v0);
    atomicAdd(&acc[((((unsigned)pa.y) >> 17) << 4) | (unsigned)k], v1);
    atomicAdd(&acc[((((unsigned)pa.z) >> 17) << 4) | (unsigned)k], v2);
    atomicAdd(&acc[((((unsigned)pa.w) >> 17) << 4) | (unsigned)k], v3);
    atomicAdd(&acc[((((unsigned)pb.x) >> 17) << 4) | (unsigned)k], v4);
    atomicAdd(&acc[((((unsigned)pb.y) >> 17) << 4) | (unsigned)k], v5);
    atomicAdd(&acc[((((unsigned)pb.z) >> 17) << 4) | (unsigned)k], v6);
    atomicAdd(&acc[((((unsigned)pb.w) >> 17) << 4) | (unsigned)k], v7);
    if (k == 0) {
      atomicAdd(&dcnt[(unsigned)pa.x >> 17], 1);
      atomicAdd(&dcnt[(unsigned)pa.y >> 17], 1);
      atomicAdd(&dcnt[(unsigned)pa.z >> 17], 1);
      atomicAdd(&dcnt[(unsigned)pa.w >> 17], 1);
      atomicAdd(&dcnt[(unsigned)pb.x >> 17], 1);
      atomicAdd(&dcnt[(unsigned)pb.y >> 17], 1);
      atomicAdd(&dcnt[(unsigned)pb.z >> 17], 1);
      atomicAdd(&dcnt[(unsigned)pb.w >> 17], 1);
    }
  }
  // tail (< 128 edges): one edge per group per iteration
  for (int ee = e + g; ee < end; ee += 16) {
    int pk = part[ee];
    float v = h[(((unsigned)pk & 0x1FFFFu) << 4) | (unsigned)k];
    unsigned dl = (unsigned)pk >> 17;
    atomicAdd(&acc[(dl << 4) | (unsigned)k], v);
    if (k == 0) atomicAdd(&dcnt[dl], 1);
  }
  __syncthreads();

  // coalesced flush: plain float4 stores into this chunk's partial buffer
  float* pout = partial + (size_t)c * nbuck * BUCKET_NODES * 16
                        + (size_t)b * BUCKET_NODES * 16;
  float4* pout4 = (float4*)pout;
  const float4* a4 = (const float4*)acc;
#pragma unroll
  for (int i = t; i < BUCKET_NODES * 4; i += 256) pout4[i] = a4[i];
  int n0 = b * BUCKET_NODES + t;
  if (dcnt[t]) atomicAdd(&cnt[n0], dcnt[t]);
  if (dcnt[t + 256]) atomicAdd(&cnt[n0 + 256], dcnt[t + 256]);
}

// ---------------- Kernel 4: reduce partials + SAGE epilogue ----------------
__global__ __launch_bounds__(256) void out_kernel(
    const float* __restrict__ h, const float* __restrict__ partial,
    const int* __restrict__ cnt,
    const float* __restrict__ wl, const float* __restrict__ bl,
    const float* __restrict__ wr, float* __restrict__ out,
    int n_nodes, int nbuck, int C) {
  __shared__ float swl[512];
  __shared__ float swr[512];
  __shared__ float sbl[32];
  int t = threadIdx.x;
  for (int i = t; i < 512; i += 256) { swl[i] = wl[i]; swr[i] = wr[i]; }
  if (t < 32) sbl[t] = bl[t];
  __syncthreads();

  int n = blockIdx.x * 256 + t;
  if (n >= n_nodes) return;

  size_t stride = (size_t)nbuck * BUCKET_NODES * 16;
  float mean[16];
#pragma unroll
  for (int k = 0; k < 16; ++k) mean[k] = 0.0f;
  for (int c = 0; c < C; ++c) {
    const float4* pr = (const float4*)(partial + c * stride + (size_t)n * 16);
    float4 p0 = pr[0], p1 = pr[1], p2 = pr[2], p3 = pr[3];
    mean[0]+=p0.x; mean[1]+=p0.y; mean[2]+=p0.z; mean[3]+=p0.w;
    mean[4]+=p1.x; mean[5]+=p1.y; mean[6]+=p1.z; mean[7]+=p1.w;
    mean[8]+=p2.x; mean[9]+=p2.y; mean[10]+=p2.z; mean[11]+=p2.w;
    mean[12]+=p3.x; mean[13]+=p3.y; mean[14]+=p3.z; mean[15]+=p3.w;
  }
  float inv = 1.0f / fmaxf((float)cnt[n], 1.0f);
#pragma unroll
  for (int k = 0; k < 16; ++k) mean[k] *= inv;

  float hr[16];
  const float4* hp = (const float4*)(h + (size_t)n * 16);
  float4 h0 = hp[0], h1 = hp[1], h2 = hp[2], h3 = hp[3];
  hr[0]=h0.x; hr[1]=h0.y; hr[2]=h0.z; hr[3]=h0.w;
  hr[4]=h1.x; hr[5]=h1.y; hr[6]=h1.z; hr[7]=h1.w;
  hr[8]=h2.x; hr[9]=h2.y; hr[10]=h2.z; hr[11]=h2.w;
  hr[12]=h3.x; hr[13]=h3.y; hr[14]=h3.z; hr[15]=h3.w;

  float o[32];
#pragma unroll
  for (int j = 0; j < 32; ++j) o[j] = sbl[j];
#pragma unroll
  for (int k = 0; k < 16; ++k) {
#pragma unroll
    for (int j = 0; j < 32; ++j) {
      o[j] += mean[k] * swl[k * 32 + j] + hr[k] * swr[k * 32 + j];
    }
  }
  float4* ow = (float4*)(out + (size_t)n * 32);
#pragma unroll
  for (int q = 0; q < 8; ++q)
    ow[q] = make_float4(o[q*4], o[q*4+1], o[q*4+2], o[q*4+3]);
}

extern "C" void kernel_launch(void* const* d_in, const int* in_sizes, int n_in,
                              void* d_out, int out_size, void* d_ws, size_t ws_size,
                              hipStream_t stream) {
  const float* x  = (const float*)d_in[0];
  const int* eidx = (const int*)d_in[1];
  const float* w1 = (const float*)d_in[2];
  const float* b1 = (const float*)d_in[3];
  const float* w2 = (const float*)d_in[4];
  const float* b2 = (const float*)d_in[5];
  const float* wl = (const float*)d_in[6];
  const float* bl = (const float*)d_in[7];
  const float* wr = (const float*)d_in[8];
  float* out = (float*)d_out;

  const int n_nodes = in_sizes[0] / D_IN_C;   // 100000
  const int n_edges = in_sizes[1] / 2;        // 3200000
  const int* src = eidx;
  const int* dst = eidx + n_edges;

  const int nbuck = (n_nodes + BUCKET_NODES - 1) / BUCKET_NODES;  // 196

  // workspace layout (all offsets 16B-aligned)
  float* h     = (float*)d_ws;                          // n_nodes*16 f32
  int* part    = (int*)(h + (size_t)n_nodes * 16);      // nbuck*CAP ints
  int* bcur    = part + (size_t)nbuck * CAP;            // 256 ints
  int* cnt     = bcur + 256;                            // nbuck*512 ints
  float* partial = (float*)(cnt + (size_t)nbuck * BUCKET_NODES);

  size_t fixed = (size_t)n_nodes * 16 * 4 + (size_t)nbuck * CAP * 4
               + 256 * 4 + (size_t)nbuck * BUCKET_NODES * 4;
  size_t per_copy = (size_t)nbuck * BUCKET_NODES * 16 * 4;  // 6.42 MB
  int C = (ws_size >= fixed + 4 * per_copy) ? 4 : 2;

  mlp_kernel<<<(n_nodes + 255) / 256, 256, 0, stream>>>(
      x, w1, b1, w2, b2, h, bcur, n_nodes);
  part_kernel<<<(n_edges + PART_CHUNK - 1) / PART_CHUNK, 256, 0, stream>>>(
      src, dst, bcur, part, cnt, nbuck, n_edges);
  acc_kernel<<<nbuck * C, 256, 0, stream>>>(
      h, part, bcur, cnt, partial, nbuck, C);
  out_kernel<<<(n_nodes + 255) / 256, 256, 0, stream>>>(
      h, partial, cnt, wl, bl, wr, out, n_nodes, nbuck, C);
}